// Round 3
// baseline (1065.659 us; speedup 1.0000x reference)
//
#include <hip/hip_runtime.h>
#include <hip/hip_bf16.h>

#define H 512
#define W 512
#define C 32
#define O 32
#define TW 32      // tile width (pixels)
#define SH 32      // rows per block (8 strips of 4)
#define NS 8       // strips per block
#define RING 12    // LDS row ring (read window 6 + write window 4 <= 12)
#define XCOLS (TW + 2)

using bf16x8 = __attribute__((ext_vector_type(8))) short;
using f32x4  = __attribute__((ext_vector_type(4))) float;

__device__ __forceinline__ unsigned short f2bf(float f) {
    union { float f; unsigned u; } c; c.f = f;
    unsigned r = c.u + 0x7fffu + ((c.u >> 16) & 1u);
    return (unsigned short)(r >> 16);
}

__device__ __forceinline__ uint4 pack8(const float* v) {
    uint4 pk;
    pk.x = (unsigned)f2bf(v[0]) | ((unsigned)f2bf(v[1]) << 16);
    pk.y = (unsigned)f2bf(v[2]) | ((unsigned)f2bf(v[3]) << 16);
    pk.z = (unsigned)f2bf(v[4]) | ((unsigned)f2bf(v[5]) << 16);
    pk.w = (unsigned)f2bf(v[6]) | ((unsigned)f2bf(v[7]) << 16);
    return pk;
}

// Reconstruct w[o, ci, 3, 3] from CP factors, store bf16 as w[s][o][ci]
// (ci contiguous => B-fragment loads are single 16B reads).
__global__ void recon_w(const float* __restrict__ k0, const float* __restrict__ k1,
                        const float* __restrict__ k2, const float* __restrict__ k3,
                        unsigned short* __restrict__ wout) {
    int idx = blockIdx.x * 256 + threadIdx.x;
    if (idx >= 9 * 32 * 32) return;
    int ci = idx & 31;
    int o  = (idx >> 5) & 31;
    int s  = idx >> 10;                 // 0..8 = dh*3+dw
    int i = o >> 4, j = (o >> 2) & 3, k = o & 3;
    int a = ci >> 4, b = (ci >> 2) & 3, c = ci & 3;
    float acc = 0.f;
    #pragma unroll
    for (int r = 0; r < 8; ++r)
        acc += k0[(i*2 + a)*8 + r] * k1[(j*4 + b)*8 + r]
             * k2[(k*4 + c)*8 + r] * k3[s*8 + r];
    wout[idx] = f2bf(acc);
}

// Strip-pipelined implicit-GEMM conv. Block = TW x SH pixels, all 32 o-chans.
// TW=32 => 25.5 KB LDS ring => 6 blocks/CU (24 waves): enough independent
// streams that each block's per-strip vmcnt/barrier stall is covered by the
// other 5 blocks. SH=32 (8 strips) amortizes the latency-exposed prologue
// to 16% of loads and keeps block churn unchanged (2048 blocks).
__launch_bounds__(256, 6)
__global__ void conv_mfma(const float* __restrict__ x,
                          const unsigned short* __restrict__ wq,
                          const float* __restrict__ bias,
                          float* __restrict__ out) {
    // [ring-row][gx][ci-slot]; ci-quad slot XOR-swizzled by x (involution,
    // same on write and read) => ds_write_b128/ds_read_b128 bank-spread.
    __shared__ __align__(16) unsigned short sx[RING][XCOLS][C];

    const int tid = threadIdx.x;
    const int bid = blockIdx.x;
    const int n  = bid >> 8;            // 256 tiles per image (16 ty x 16 tx)
    const int ty = (bid >> 4) & 15;
    const int tx = bid & 15;
    const int y0 = ty * SH, x0 = tx * TW;

    const int lane = tid & 63;
    const int wave = tid >> 6;          // wave owns row (wave) of each strip
    const int pix  = lane & 15;
    const int quad = lane >> 4;
    const int col  = lane & 31;         // staging column within tile
    const int half = lane >> 5;         // staging row-within-pair

    // B fragments in registers (amortized over NS strips):
    // B[k=ci=quad*8+j][n=o=h*16+pix]
    bf16x8 bw[9][2];
    #pragma unroll
    for (int s = 0; s < 9; ++s)
        #pragma unroll
        for (int h = 0; h < 2; ++h)
            bw[s][h] = *(const bf16x8*)(wq + ((s*32 + h*16 + pix)*32 + quad*8));

    // ---- prologue: stage ring rows r=0..5 (gy = y0-1+r) ----
    for (int task = tid; task < 6 * 4 * XCOLS; task += 256) {
        int gxl = task % XCOLS;
        int t2  = task / XCOLS;
        int ciq = t2 & 3;
        int r   = t2 >> 2;              // 0..5 == ring slot
        int gy = y0 - 1 + r;            // < H always here
        int gx = x0 + gxl - 1;
        bool inb = (gy >= 0) && (gx >= 0) && (gx < W);
        const float* p = x + (((n*C + ciq*8)*H + gy)*W + gx);
        float v[8];
        #pragma unroll
        for (int j2 = 0; j2 < 8; ++j2) v[j2] = inb ? p[j2 * H * W] : 0.f;
        int pos = ciq ^ ((gxl >> 1) & 3);
        *(uint4*)&sx[r][gxl][pos * 8] = pack8(v);
    }
    __syncthreads();

    const float b0 = bias[pix];
    const float b1 = bias[16 + pix];

    int rbase = 0;
    for (int s = 0; s < NS; ++s) {
        const bool more = (s + 1 < NS);

        // ---- issue global loads for strip s+1 (rows gy = y0+4s+5 .. +8) ----
        // main: wave w -> planes ciq=w; lane covers (row-pair, col):
        // row k = 2*rp + half, column gx = x0 + col (coalesced 128B x2)
        float v[2][8];
        float vh[8];
        if (more) {
            #pragma unroll
            for (int rp = 0; rp < 2; ++rp) {
                int gy = y0 + 4*s + 5 + 2*rp + half;
                bool inb = (gy < H);
                const float* p = x + (((n*C + wave*8)*H + gy)*W + x0 + col);
                #pragma unroll
                for (int j2 = 0; j2 < 8; ++j2)
                    v[rp][j2] = inb ? p[j2 * H * W] : 0.f;
            }
            // halo columns gxl in {0, XCOLS-1}: 32 tasks on threads 0..31
            if (tid < 32) {
                int hcol = (tid & 1) ? (XCOLS - 1) : 0;
                int hciq = (tid >> 1) & 3;
                int hrow = tid >> 3;
                int gy = y0 + 4*s + 5 + hrow;
                int gx = x0 + hcol - 1;
                bool inb = (gy < H) && (gx >= 0) && (gx < W);
                const float* p = x + (((n*C + hciq*8)*H + gy)*W + gx);
                #pragma unroll
                for (int j2 = 0; j2 < 8; ++j2)
                    vh[j2] = inb ? p[j2 * H * W] : 0.f;
            }
        }

        // ---- compute strip s (reads ring slots rbase .. rbase+5) ----
        const int gy_out = y0 + 4*s + wave;
        #pragma unroll
        for (int mt = 0; mt < 2; ++mt) {
            const int xm = mt << 4;
            f32x4 acc0 = {0.f, 0.f, 0.f, 0.f};
            f32x4 acc1 = {0.f, 0.f, 0.f, 0.f};
            #pragma unroll
            for (int stp = 0; stp < 9; ++stp) {
                const int dy = stp / 3, dx = stp % 3;   // const-folded
                int sl = rbase + wave + dy; if (sl >= RING) sl -= RING;
                const int xp = xm + pix + dx;
                const int pos = quad ^ ((xp >> 1) & 3); // same involution
                bf16x8 a = *(const bf16x8*)&sx[sl][xp][pos * 8];
                acc0 = __builtin_amdgcn_mfma_f32_16x16x32_bf16(a, bw[stp][0], acc0, 0, 0, 0);
                acc1 = __builtin_amdgcn_mfma_f32_16x16x32_bf16(a, bw[stp][1], acc1, 0, 0, 0);
            }
            // D: m = quad*4 + reg (pixel), n = pix (o)
            const int base0 = ((n*O + pix     ) * H + gy_out) * W + x0 + xm + quad*4;
            const int base1 = ((n*O + 16 + pix) * H + gy_out) * W + x0 + xm + quad*4;
            f32x4 o0 = acc0 + b0;
            f32x4 o1 = acc1 + b1;
            *(f32x4*)(out + base0) = o0;
            *(f32x4*)(out + base1) = o1;
        }

        // ---- pack + ds_write staged rows into ring slots rbase+6..rbase+9 ----
        // (disjoint from read window rbase..rbase+5 mod 12; prior readers of
        // these slots passed two barriers ago)
        if (more) {
            #pragma unroll
            for (int rp = 0; rp < 2; ++rp) {
                int k = 2*rp + half;
                int sl = rbase + 6 + k; if (sl >= RING) sl -= RING;
                int gxl = col + 1;
                int pos = wave ^ ((gxl >> 1) & 3);
                *(uint4*)&sx[sl][gxl][pos * 8] = pack8(v[rp]);
            }
            if (tid < 32) {
                int hcol = (tid & 1) ? (XCOLS - 1) : 0;
                int hciq = (tid >> 1) & 3;
                int hrow = tid >> 3;
                int sl = rbase + 6 + hrow; if (sl >= RING) sl -= RING;
                int pos = hciq ^ ((hcol >> 1) & 3);
                *(uint4*)&sx[sl][hcol][pos * 8] = pack8(vh);
            }
            __syncthreads();
        }

        rbase += 4; if (rbase >= RING) rbase -= RING;
    }
}

extern "C" void kernel_launch(void* const* d_in, const int* in_sizes, int n_in,
                              void* d_out, int out_size, void* d_ws, size_t ws_size,
                              hipStream_t stream) {
    const float* x    = (const float*)d_in[0];
    const float* k1_  = (const float*)d_in[2];
    const float* k0   = (const float*)d_in[1];
    const float* k2   = (const float*)d_in[3];
    const float* k3   = (const float*)d_in[4];
    const float* bias = (const float*)d_in[5];
    float* out = (float*)d_out;
    unsigned short* wbuf = (unsigned short*)d_ws;  // 9216 bf16 = 18 KB

    recon_w<<<36, 256, 0, stream>>>(k0, k1_, k2, k3, wbuf);
    // 8 images * (512/SH=16) * (512/TW=16) = 2048 blocks
    conv_mfma<<<2048, 256, 0, stream>>>(x, wbuf, bias, out);
}

// Round 4
// 497.773 us; speedup vs baseline: 2.1409x; 2.1409x over previous
//
#include <hip/hip_runtime.h>
#include <hip/hip_bf16.h>

#define H 512
#define W 512
#define C 32
#define O 32
#define TW 32      // tile width (pixels)
#define SH 32      // rows per block (8 strips of 4)
#define NS 8       // strips per block
#define RING 12    // LDS row ring (read window 6 + write window 4 <= 12)
#define XCOLS (TW + 2)

using bf16x8 = __attribute__((ext_vector_type(8))) short;
using f32x4  = __attribute__((ext_vector_type(4))) float;

__device__ __forceinline__ unsigned short f2bf(float f) {
    union { float f; unsigned u; } c; c.f = f;
    unsigned r = c.u + 0x7fffu + ((c.u >> 16) & 1u);
    return (unsigned short)(r >> 16);
}

__device__ __forceinline__ uint4 pack8(const float* v) {
    uint4 pk;
    pk.x = (unsigned)f2bf(v[0]) | ((unsigned)f2bf(v[1]) << 16);
    pk.y = (unsigned)f2bf(v[2]) | ((unsigned)f2bf(v[3]) << 16);
    pk.z = (unsigned)f2bf(v[4]) | ((unsigned)f2bf(v[5]) << 16);
    pk.w = (unsigned)f2bf(v[6]) | ((unsigned)f2bf(v[7]) << 16);
    return pk;
}

__device__ __forceinline__ uint2 pack4(const float* v) {
    uint2 pk;
    pk.x = (unsigned)f2bf(v[0]) | ((unsigned)f2bf(v[1]) << 16);
    pk.y = (unsigned)f2bf(v[2]) | ((unsigned)f2bf(v[3]) << 16);
    return pk;
}

// Reconstruct w[o, ci, 3, 3] from CP factors, store bf16 as w[s][o][ci]
// (ci contiguous => B-fragment loads are single 16B reads).
__global__ void recon_w(const float* __restrict__ k0, const float* __restrict__ k1,
                        const float* __restrict__ k2, const float* __restrict__ k3,
                        unsigned short* __restrict__ wout) {
    int idx = blockIdx.x * 256 + threadIdx.x;
    if (idx >= 9 * 32 * 32) return;
    int ci = idx & 31;
    int o  = (idx >> 5) & 31;
    int s  = idx >> 10;                 // 0..8 = dh*3+dw
    int i = o >> 4, j = (o >> 2) & 3, k = o & 3;
    int a = ci >> 4, b = (ci >> 2) & 3, c = ci & 3;
    float acc = 0.f;
    #pragma unroll
    for (int r = 0; r < 8; ++r)
        acc += k0[(i*2 + a)*8 + r] * k1[(j*4 + b)*8 + r]
             * k2[(k*4 + c)*8 + r] * k3[s*8 + r];
    wout[idx] = f2bf(acc);
}

// Strip-pipelined implicit-GEMM conv. Block = TW x SH pixels, all 32 o-chans.
// Wave = (row-pair wr, o-half oh): each wave holds only 9 B-fragments
// (36 VGPR, was 72) so the whole kernel fits ~80 VGPR => 6 waves/EU
// feasible; LDS ring 25.5 KB => 6 blocks/CU (24 waves) is the residency cap.
// Per strip: issue next strip's global loads (held in regs), compute
// current strip, then vmcnt+pack+ds_write+barrier. Loads stay in flight
// under the MFMA phase.
__launch_bounds__(256, 5)
__global__ void conv_mfma(const float* __restrict__ x,
                          const unsigned short* __restrict__ wq,
                          const float* __restrict__ bias,
                          float* __restrict__ out) {
    // [ring-row][gx][ci-slot]; ci-quad slot XOR-swizzled by x (involution,
    // same on write and read) => ds_write_b128/ds_read_b128 bank-spread.
    __shared__ __align__(16) unsigned short sx[RING][XCOLS][C];

    const int tid = threadIdx.x;
    const int bid = blockIdx.x;
    const int n  = bid >> 8;            // 256 tiles per image (16 ty x 16 tx)
    const int ty = (bid >> 4) & 15;
    const int tx = bid & 15;
    const int y0 = ty * SH, x0 = tx * TW;

    const int lane = tid & 63;
    const int wave = tid >> 6;
    const int pix  = lane & 15;
    const int quad = lane >> 4;
    const int col  = lane & 31;         // staging column within tile
    const int half = lane >> 5;         // staging row-within-pair
    const int wr = wave >> 1;           // compute: row-pair of strip
    const int oh = wave & 1;            // compute: o-half (0..15 / 16..31)

    // B fragments: one o-half per wave. B[k=ci=quad*8+j][n=o=oh*16+pix]
    bf16x8 bw[9];
    #pragma unroll
    for (int s = 0; s < 9; ++s)
        bw[s] = *(const bf16x8*)(wq + ((s*32 + oh*16 + pix)*32 + quad*8));

    // ---- prologue: stage ring rows r=0..5 (gy = y0-1+r) ----
    for (int task = tid; task < 6 * 4 * XCOLS; task += 256) {
        int gxl = task % XCOLS;
        int t2  = task / XCOLS;
        int ciq = t2 & 3;
        int r   = t2 >> 2;              // 0..5 == ring slot
        int gy = y0 - 1 + r;            // < H always here
        int gx = x0 + gxl - 1;
        bool inb = (gy >= 0) && (gx >= 0) && (gx < W);
        const float* p = x + (((n*C + ciq*8)*H + gy)*W + gx);
        float v[8];
        #pragma unroll
        for (int j2 = 0; j2 < 8; ++j2) v[j2] = inb ? p[j2 * H * W] : 0.f;
        int pos = ciq ^ ((gxl >> 1) & 3);
        *(uint4*)&sx[r][gxl][pos * 8] = pack8(v);
    }
    __syncthreads();

    const float bz = bias[oh * 16 + pix];

    int rbase = 0;
    for (int s = 0; s < NS; ++s) {
        const bool more = (s + 1 < NS);

        // ---- issue global loads for strip s+1 (rows gy = y0+4s+5 .. +8) ----
        // main: wave w stages planes ciq=w; lane covers (row-pair, col):
        // row k = 2*rp + half, column gx = x0 + col (coalesced 128B x2)
        float v[2][8];
        float vh[4];
        if (more) {
            #pragma unroll
            for (int rp = 0; rp < 2; ++rp) {
                int gy = y0 + 4*s + 5 + 2*rp + half;
                bool inb = (gy < H);
                const float* p = x + (((n*C + wave*8)*H + gy)*W + x0 + col);
                #pragma unroll
                for (int j2 = 0; j2 < 8; ++j2)
                    v[rp][j2] = inb ? p[j2 * H * W] : 0.f;
            }
            // halo columns gxl in {0, XCOLS-1}: 64 tasks (4 floats each)
            // on threads 0..63.  bits: b0=col, b1=ci-subhalf, b2..3=ciq,
            // b4..5=row
            if (tid < 64) {
                int hcol = (tid & 1) ? (XCOLS - 1) : 0;
                int hh   = (tid >> 1) & 1;
                int hciq = (tid >> 2) & 3;
                int hrow = tid >> 4;
                int gy = y0 + 4*s + 5 + hrow;
                int gx = x0 + hcol - 1;
                bool inb = (gy < H) && (gx >= 0) && (gx < W);
                const float* p = x + (((n*C + hciq*8 + hh*4)*H + gy)*W + gx);
                #pragma unroll
                for (int j2 = 0; j2 < 4; ++j2)
                    vh[j2] = inb ? p[j2 * H * W] : 0.f;
            }
        }

        // ---- compute strip s (reads ring slots rbase .. rbase+5) ----
        // wave (wr, oh): rows 2wr, 2wr+1; x-tiles xm=0,16 as twin acc chains
        #pragma unroll
        for (int rr = 0; rr < 2; ++rr) {
            const int row = 2*wr + rr;
            f32x4 accA = {0.f, 0.f, 0.f, 0.f};
            f32x4 accB = {0.f, 0.f, 0.f, 0.f};
            #pragma unroll
            for (int dy = 0; dy < 3; ++dy) {
                int sl = rbase + row + dy; if (sl >= RING) sl -= RING;
                #pragma unroll
                for (int dx = 0; dx < 3; ++dx) {
                    const int stp = dy * 3 + dx;
                    const int xpA = pix + dx;        // xm = 0
                    const int xpB = 16 + pix + dx;   // xm = 16
                    const int posA = quad ^ ((xpA >> 1) & 3);
                    const int posB = quad ^ ((xpB >> 1) & 3);
                    bf16x8 a0 = *(const bf16x8*)&sx[sl][xpA][posA * 8];
                    bf16x8 a1 = *(const bf16x8*)&sx[sl][xpB][posB * 8];
                    accA = __builtin_amdgcn_mfma_f32_16x16x32_bf16(a0, bw[stp], accA, 0, 0, 0);
                    accB = __builtin_amdgcn_mfma_f32_16x16x32_bf16(a1, bw[stp], accB, 0, 0, 0);
                }
            }
            // D: m = quad*4 + reg (pixel), n = pix (o)
            const int gy_out = y0 + 4*s + row;
            const int base = ((n*O + oh*16 + pix) * H + gy_out) * W + x0 + quad*4;
            f32x4 oA = accA + bz;
            f32x4 oB = accB + bz;
            *(f32x4*)(out + base)      = oA;
            *(f32x4*)(out + base + 16) = oB;
        }

        // ---- pack + ds_write staged rows into ring slots rbase+6..rbase+9 ----
        // (disjoint from read window rbase..rbase+5 mod 12; prior readers of
        // these slots passed two barriers ago)
        if (more) {
            #pragma unroll
            for (int rp = 0; rp < 2; ++rp) {
                int k = 2*rp + half;
                int sl = rbase + 6 + k; if (sl >= RING) sl -= RING;
                int gxl = col + 1;
                int pos = wave ^ ((gxl >> 1) & 3);
                *(uint4*)&sx[sl][gxl][pos * 8] = pack8(v[rp]);
            }
            if (tid < 64) {
                int hcol = (tid & 1) ? (XCOLS - 1) : 0;
                int hh   = (tid >> 1) & 1;
                int hciq = (tid >> 2) & 3;
                int hrow = tid >> 4;
                int sl = rbase + 6 + hrow; if (sl >= RING) sl -= RING;
                int pos = hciq ^ ((hcol >> 1) & 3);
                *(uint2*)&sx[sl][hcol][pos * 8 + hh * 4] = pack4(vh);
            }
            __syncthreads();
        }

        rbase += 4; if (rbase >= RING) rbase -= RING;
    }
}

extern "C" void kernel_launch(void* const* d_in, const int* in_sizes, int n_in,
                              void* d_out, int out_size, void* d_ws, size_t ws_size,
                              hipStream_t stream) {
    const float* x    = (const float*)d_in[0];
    const float* k0   = (const float*)d_in[1];
    const float* k1   = (const float*)d_in[2];
    const float* k2   = (const float*)d_in[3];
    const float* k3   = (const float*)d_in[4];
    const float* bias = (const float*)d_in[5];
    float* out = (float*)d_out;
    unsigned short* wbuf = (unsigned short*)d_ws;  // 9216 bf16 = 18 KB

    recon_w<<<36, 256, 0, stream>>>(k0, k1, k2, k3, wbuf);
    // 8 images * (512/SH=16) * (512/TW=16) = 2048 blocks
    conv_mfma<<<2048, 256, 0, stream>>>(x, wbuf, bias, out);
}

// Round 5
// 482.545 us; speedup vs baseline: 2.2084x; 1.0316x over previous
//
#include <hip/hip_runtime.h>
#include <hip/hip_bf16.h>

#define H 512
#define W 512
#define C 32
#define O 32
#define TW 32      // tile width (pixels)
#define SH 32      // rows per block (8 strips of 4)
#define NS 8       // strips per block
#define RING 12    // LDS row ring (read window 6 + write window 4 <= 12)
#define XCOLS (TW + 2)

using bf16x8 = __attribute__((ext_vector_type(8))) short;
using f32x4  = __attribute__((ext_vector_type(4))) float;

__device__ __forceinline__ unsigned short f2bf(float f) {
    union { float f; unsigned u; } c; c.f = f;
    unsigned r = c.u + 0x7fffu + ((c.u >> 16) & 1u);
    return (unsigned short)(r >> 16);
}

__device__ __forceinline__ uint4 pack8(const float* v) {
    uint4 pk;
    pk.x = (unsigned)f2bf(v[0]) | ((unsigned)f2bf(v[1]) << 16);
    pk.y = (unsigned)f2bf(v[2]) | ((unsigned)f2bf(v[3]) << 16);
    pk.z = (unsigned)f2bf(v[4]) | ((unsigned)f2bf(v[5]) << 16);
    pk.w = (unsigned)f2bf(v[6]) | ((unsigned)f2bf(v[7]) << 16);
    return pk;
}

__device__ __forceinline__ uint2 pack4(const float* v) {
    uint2 pk;
    pk.x = (unsigned)f2bf(v[0]) | ((unsigned)f2bf(v[1]) << 16);
    pk.y = (unsigned)f2bf(v[2]) | ((unsigned)f2bf(v[3]) << 16);
    return pk;
}

// Reconstruct w[o, ci, 3, 3] from CP factors, store bf16 as w[s][o][ci]
// (ci contiguous => B-fragment loads are single 16B reads).
__global__ void recon_w(const float* __restrict__ k0, const float* __restrict__ k1,
                        const float* __restrict__ k2, const float* __restrict__ k3,
                        unsigned short* __restrict__ wout) {
    int idx = blockIdx.x * 256 + threadIdx.x;
    if (idx >= 9 * 32 * 32) return;
    int ci = idx & 31;
    int o  = (idx >> 5) & 31;
    int s  = idx >> 10;                 // 0..8 = dh*3+dw
    int i = o >> 4, j = (o >> 2) & 3, k = o & 3;
    int a = ci >> 4, b = (ci >> 2) & 3, c = ci & 3;
    float acc = 0.f;
    #pragma unroll
    for (int r = 0; r < 8; ++r)
        acc += k0[(i*2 + a)*8 + r] * k1[(j*4 + b)*8 + r]
             * k2[(k*4 + c)*8 + r] * k3[s*8 + r];
    wout[idx] = f2bf(acc);
}

// Strip-pipelined implicit-GEMM conv. Block = TW x SH pixels, all 32 o-chans.
// Wave = (row-pair wr, o-half oh): 9 B-fragments per wave (36 VGPR).
// XCD swizzle: bid' = (bid&7)*256 + bid>>3 => each XCD owns ONE image in
// raster order, so tx+-1 / ty+-1 neighbors share an L2 => halo 64B sectors
// (channel-strided dword gathers) become L2 hits instead of HBM refetch.
// Prefetch for strip s+1 is issued before the MFMA phase and PINNED there
// by sched_barrier(0) (R4 lesson: the compiler sank the loads to their
// ds_write use, VGPR 48 < live-set => overlap existed only in source).
__launch_bounds__(256, 4)
__global__ void conv_mfma(const float* __restrict__ x,
                          const unsigned short* __restrict__ wq,
                          const float* __restrict__ bias,
                          float* __restrict__ out) {
    // [ring-row][gx][ci-slot]; ci-quad slot XOR-swizzled by x (involution,
    // same on write and read) => ds_write_b128/ds_read_b128 bank-spread.
    __shared__ __align__(16) unsigned short sx[RING][XCOLS][C];

    const int tid = threadIdx.x;
    const int bid = ((blockIdx.x & 7) << 8) | (blockIdx.x >> 3);  // XCD swizzle
    const int n  = bid >> 8;            // 256 tiles per image (16 ty x 16 tx)
    const int ty = (bid >> 4) & 15;
    const int tx = bid & 15;
    const int y0 = ty * SH, x0 = tx * TW;

    const int lane = tid & 63;
    const int wave = tid >> 6;
    const int pix  = lane & 15;
    const int quad = lane >> 4;
    const int col  = lane & 31;         // staging column within tile
    const int half = lane >> 5;         // staging row-within-pair
    const int wr = wave >> 1;           // compute: row-pair of strip
    const int oh = wave & 1;            // compute: o-half (0..15 / 16..31)

    // B fragments: one o-half per wave. B[k=ci=quad*8+j][n=o=oh*16+pix]
    bf16x8 bw[9];
    #pragma unroll
    for (int s = 0; s < 9; ++s)
        bw[s] = *(const bf16x8*)(wq + ((s*32 + oh*16 + pix)*32 + quad*8));

    // ---- prologue: stage ring rows r=0..5 (gy = y0-1+r) ----
    for (int task = tid; task < 6 * 4 * XCOLS; task += 256) {
        int gxl = task % XCOLS;
        int t2  = task / XCOLS;
        int ciq = t2 & 3;
        int r   = t2 >> 2;              // 0..5 == ring slot
        int gy = y0 - 1 + r;            // < H always here
        int gx = x0 + gxl - 1;
        bool inb = (gy >= 0) && (gx >= 0) && (gx < W);
        const float* p = x + (((n*C + ciq*8)*H + gy)*W + gx);
        float v[8];
        #pragma unroll
        for (int j2 = 0; j2 < 8; ++j2) v[j2] = inb ? p[j2 * H * W] : 0.f;
        int pos = ciq ^ ((gxl >> 1) & 3);
        *(uint4*)&sx[r][gxl][pos * 8] = pack8(v);
    }
    __syncthreads();

    const float bz = bias[oh * 16 + pix];

    int rbase = 0;
    for (int s = 0; s < NS; ++s) {
        const bool more = (s + 1 < NS);

        // ---- issue global loads for strip s+1 (rows gy = y0+4s+5 .. +8) ----
        // main: wave w stages planes ciq=w; lane covers (row-pair, col):
        // row k = 2*rp + half, column gx = x0 + col (coalesced 128B x2)
        float v[2][8];
        float vh[4];
        if (more) {
            #pragma unroll
            for (int rp = 0; rp < 2; ++rp) {
                int gy = y0 + 4*s + 5 + 2*rp + half;
                bool inb = (gy < H);
                const float* p = x + (((n*C + wave*8)*H + gy)*W + x0 + col);
                #pragma unroll
                for (int j2 = 0; j2 < 8; ++j2)
                    v[rp][j2] = inb ? p[j2 * H * W] : 0.f;
            }
            // halo columns gxl in {0, XCOLS-1}: 64 tasks (4 floats each)
            // bits: b0=col, b1=ci-subhalf, b2..3=ciq, b4..5=row
            if (tid < 64) {
                int hcol = (tid & 1) ? (XCOLS - 1) : 0;
                int hh   = (tid >> 1) & 1;
                int hciq = (tid >> 2) & 3;
                int hrow = tid >> 4;
                int gy = y0 + 4*s + 5 + hrow;
                int gx = x0 + hcol - 1;
                bool inb = (gy < H) && (gx >= 0) && (gx < W);
                const float* p = x + (((n*C + hciq*8 + hh*4)*H + gy)*W + gx);
                #pragma unroll
                for (int j2 = 0; j2 < 4; ++j2)
                    vh[j2] = inb ? p[j2 * H * W] : 0.f;
            }
        }
        // Pin the loads above this point: they must issue before the MFMA
        // phase, with their vmcnt wait deferred to the ds_write below.
        __builtin_amdgcn_sched_barrier(0);

        // ---- compute strip s (reads ring slots rbase .. rbase+5) ----
        // wave (wr, oh): rows 2wr, 2wr+1; x-tiles xm=0,16 as twin acc chains
        #pragma unroll
        for (int rr = 0; rr < 2; ++rr) {
            const int row = 2*wr + rr;
            f32x4 accA = {0.f, 0.f, 0.f, 0.f};
            f32x4 accB = {0.f, 0.f, 0.f, 0.f};
            #pragma unroll
            for (int dy = 0; dy < 3; ++dy) {
                int sl = rbase + row + dy; if (sl >= RING) sl -= RING;
                #pragma unroll
                for (int dx = 0; dx < 3; ++dx) {
                    const int stp = dy * 3 + dx;
                    const int xpA = pix + dx;        // xm = 0
                    const int xpB = 16 + pix + dx;   // xm = 16
                    const int posA = quad ^ ((xpA >> 1) & 3);
                    const int posB = quad ^ ((xpB >> 1) & 3);
                    bf16x8 a0 = *(const bf16x8*)&sx[sl][xpA][posA * 8];
                    bf16x8 a1 = *(const bf16x8*)&sx[sl][xpB][posB * 8];
                    accA = __builtin_amdgcn_mfma_f32_16x16x32_bf16(a0, bw[stp], accA, 0, 0, 0);
                    accB = __builtin_amdgcn_mfma_f32_16x16x32_bf16(a1, bw[stp], accB, 0, 0, 0);
                }
            }
            // D: m = quad*4 + reg (pixel), n = pix (o)
            const int gy_out = y0 + 4*s + row;
            const int base = ((n*O + oh*16 + pix) * H + gy_out) * W + x0 + quad*4;
            f32x4 oA = accA + bz;
            f32x4 oB = accB + bz;
            *(f32x4*)(out + base)      = oA;
            *(f32x4*)(out + base + 16) = oB;
        }

        // ---- pack + ds_write staged rows into ring slots rbase+6..rbase+9 ----
        // (disjoint from read window rbase..rbase+5 mod 12; prior readers of
        // these slots passed two barriers ago)
        if (more) {
            #pragma unroll
            for (int rp = 0; rp < 2; ++rp) {
                int k = 2*rp + half;
                int sl = rbase + 6 + k; if (sl >= RING) sl -= RING;
                int gxl = col + 1;
                int pos = wave ^ ((gxl >> 1) & 3);
                *(uint4*)&sx[sl][gxl][pos * 8] = pack8(v[rp]);
            }
            if (tid < 64) {
                int hcol = (tid & 1) ? (XCOLS - 1) : 0;
                int hh   = (tid >> 1) & 1;
                int hciq = (tid >> 2) & 3;
                int hrow = tid >> 4;
                int sl = rbase + 6 + hrow; if (sl >= RING) sl -= RING;
                int pos = hciq ^ ((hcol >> 1) & 3);
                *(uint2*)&sx[sl][hcol][pos * 8 + hh * 4] = pack4(vh);
            }
            __syncthreads();
        }

        rbase += 4; if (rbase >= RING) rbase -= RING;
    }
}

extern "C" void kernel_launch(void* const* d_in, const int* in_sizes, int n_in,
                              void* d_out, int out_size, void* d_ws, size_t ws_size,
                              hipStream_t stream) {
    const float* x    = (const float*)d_in[0];
    const float* k0   = (const float*)d_in[1];
    const float* k1   = (const float*)d_in[2];
    const float* k2   = (const float*)d_in[3];
    const float* k3   = (const float*)d_in[4];
    const float* bias = (const float*)d_in[5];
    float* out = (float*)d_out;
    unsigned short* wbuf = (unsigned short*)d_ws;  // 9216 bf16 = 18 KB

    recon_w<<<36, 256, 0, stream>>>(k0, k1, k2, k3, wbuf);
    // 8 images * (512/SH=16) * (512/TW=16) = 2048 blocks
    conv_mfma<<<2048, 256, 0, stream>>>(x, wbuf, bias, out);
}